// Round 6
// baseline (256.218 us; speedup 1.0000x reference)
//
#include <hip/hip_runtime.h>
#include <hip/hip_bf16.h>
#include <cstdint>

#define S_ 2048
#define M_ 512
#define L_ 2560
#define D_ 1024
#define F_ 4096
#define H_ 16
#define DH_ 64
#define W_ 256
#define NR_ 513
#define NRP_ 640

typedef unsigned int uint32;
typedef __attribute__((ext_vector_type(8))) short bf16x8;
typedef __attribute__((ext_vector_type(4))) float f32x4;

__device__ __forceinline__ ushort f2bf(float f) {
  uint32 u = __builtin_bit_cast(uint32, f);
  u += 0x7FFFu + ((u >> 16) & 1u);
  return (ushort)(u >> 16);
}
__device__ __forceinline__ float bf2f(ushort s) {
  uint32 u = ((uint32)s) << 16;
  return __builtin_bit_cast(float, u);
}
__device__ __forceinline__ ushort4 pack4(float4 vf) {
  ushort4 r;
  r.x = f2bf(vf.x); r.y = f2bf(vf.y); r.z = f2bf(vf.z); r.w = f2bf(vf.w);
  return r;
}
__device__ __forceinline__ float gelu_tanh(float x) {
  float t = 0.7978845608028654f * x * (1.f + 0.044715f * x * x);
  float e = __expf(2.f * t);
  float th = 1.f - 2.f / (e + 1.f);
  return 0.5f * x * (1.f + th);
}

// async global(16B/lane) -> LDS, wave-uniform LDS base + lane*16
__device__ __forceinline__ void gld_lds16(const ushort* g, ushort* l) {
  __builtin_amdgcn_global_load_lds((const __attribute__((address_space(1))) void*)g,
                                   (__attribute__((address_space(3))) void*)l, 16, 0, 0);
}

// ================= fused prep: 7 weight transposes + kv pack + sinusoid =================
__device__ __forceinline__ void tr_tile(const float* __restrict__ in, ushort* __restrict__ out,
                                        int R, int C, int c0, int r0, int tx, int ty,
                                        float (*tile)[33]) {
#pragma unroll
  for (int i = 0; i < 4; i++)
    tile[ty + i * 8][tx] = in[(size_t)(r0 + ty + i * 8) * C + c0 + tx];
  __syncthreads();
#pragma unroll
  for (int i = 0; i < 4; i++)
    out[(size_t)(c0 + ty + i * 8) * R + r0 + tx] = f2bf(tile[tx][ty + i * 8]);
}

__global__ __launch_bounds__(256)
void prep_kernel(const float* __restrict__ x, const float* __restrict__ mem,
                 const float* __restrict__ Wq, const float* __restrict__ Wk,
                 const float* __restrict__ Wv, const float* __restrict__ Wo,
                 const float* __restrict__ Wr, const float* __restrict__ W1,
                 const float* __restrict__ W2,
                 ushort* __restrict__ WqT, ushort* __restrict__ WkT,
                 ushort* __restrict__ WvT, ushort* __restrict__ WoT,
                 ushort* __restrict__ WrT, ushort* __restrict__ W1T,
                 ushort* __restrict__ W2T,
                 ushort* __restrict__ kvb, ushort* __restrict__ remb) {
  __shared__ float tile[32][33];
  const int bid = blockIdx.x;
  const int tid = threadIdx.x;
  const int tx = tid & 31, ty = tid >> 5;

  if (bid < 5120) {
    const int which = bid >> 10, idx = bid & 1023;
    const float* ins[5] = {Wq, Wk, Wv, Wo, Wr};
    ushort* outs[5] = {WqT, WkT, WvT, WoT, WrT};
    tr_tile(ins[which], outs[which], 1024, 1024, (idx & 31) * 32, (idx >> 5) * 32, tx, ty, tile);
  } else if (bid < 9216) {
    const int idx = bid - 5120;
    tr_tile(W1, W1T, 1024, 4096, (idx % 128) * 32, (idx / 128) * 32, tx, ty, tile);
  } else if (bid < 13312) {
    const int idx = bid - 9216;
    tr_tile(W2, W2T, 4096, 1024, (idx & 31) * 32, (idx >> 5) * 32, tx, ty, tile);
  } else if (bid < 15872) {
    const int k = (bid - 13312) * 256 + tid;
    const int l = k >> 8, c = k & 255;
    const float4* src = (l < M_) ? (const float4*)(mem + (size_t)l * D_)
                                 : (const float4*)(x + (size_t)(l - M_) * D_);
    ((ushort4*)kvb)[k] = pack4(src[c]);
  } else {
    const int idx = (bid - 15872) * 256 + tid;
    const int r = idx >> 9, f = idx & 511;
    if (r < NR_) {
      float invf = expf(-(float)f * (9.210340371976184f / 512.0f));
      float ang = (float)(r - W_) * invf;
      remb[(size_t)r * D_ + f] = f2bf(sinf(ang));
      remb[(size_t)r * D_ + 512 + f] = f2bf(cosf(ang));
    } else if (r < NRP_) {
      remb[(size_t)r * D_ + f] = 0;
      remb[(size_t)r * D_ + 512 + f] = 0;
    }
  }
}

// ================= MFMA GEMM core: gload_lds + NBUF-deep LDS ring, counted vmcnt ======
template <int BM, int EPI, int SPLITK>
__device__ __forceinline__
void gemm_core(const ushort* __restrict__ A, const ushort* __restrict__ BT,
               void* __restrict__ Cout, void* __restrict__ Cout2,
               const float* __restrict__ bias, int Msz, int Nsz, int Ksz, int Kstride,
               int gx, int bid, int nwg, ushort* smem) {
  constexpr int PA = BM * 8 + 16;
  constexpr int PB = 128 * 8 + 16;
  constexpr int MFR = BM / 32;
  constexpr int NA = BM / 64;
  constexpr int NBUF = (BM == 64) ? 4 : 3;
  const int tid = threadIdx.x;
  const int wave = tid >> 6, lane = tid & 63;
  const int wr = wave >> 1, wc = wave & 1;

  const int q = nwg >> 3;
  const int swz = (bid & 7) * q + (bid >> 3);
  const int gy = Msz / BM;
  const int bx = swz % gx;
  const int rest = swz / gx;
  const int by = rest % gy;
  const int bz = rest / gy;

  const int brow = by * BM, bcol = bx * 128;
  const int koff = (SPLITK == 2) ? bz * Ksz : 0;

  ushort* As = smem;
  ushort* Bs = smem + NBUF * 4 * PA;

  const ushort* ag[NA]; int alo[NA];
#pragma unroll
  for (int i = 0; i < NA; i++) {
    int li = i * 4 + wave;
    int kg, rowbase;
    if constexpr (BM == 128) { kg = li >> 1; rowbase = (li & 1) * 64; }
    else { kg = li; rowbase = 0; }
    ag[i] = A + (size_t)(brow + rowbase + lane) * Kstride + koff + kg * 8;
    alo[i] = kg * PA + rowbase * 8;
  }
  const ushort* bg[2]; int blo[2];
#pragma unroll
  for (int i = 0; i < 2; i++) {
    int li = i * 4 + wave;
    int kg = li >> 1, rowbase = (li & 1) * 64;
    bg[i] = BT + (size_t)(bcol + rowbase + lane) * Kstride + koff + kg * 8;
    blo[i] = kg * PB + rowbase * 8;
  }

  f32x4 acc[MFR][4] = {};
  const int kgf = lane >> 4, fr = lane & 15;
  const int nk = Ksz >> 5;

  auto stage = [&](int t, int buf) {
    const int ko = t * 32;
    ushort* ab = As + buf * 4 * PA;
    ushort* bb = Bs + buf * 4 * PB;
#pragma unroll
    for (int i = 0; i < NA; i++) gld_lds16(ag[i] + ko, ab + alo[i]);
#pragma unroll
    for (int i = 0; i < 2; i++) gld_lds16(bg[i] + ko, bb + blo[i]);
  };

#pragma unroll
  for (int i = 0; i < NBUF - 1; i++) stage(i, i);

  int cur = 0;
  for (int t = 0; t < nk; t++) {
    if (t + NBUF - 2 < nk) {
      if constexpr (NBUF == 4) asm volatile("s_waitcnt vmcnt(6)" ::: "memory");
      else asm volatile("s_waitcnt vmcnt(4)" ::: "memory");
    } else {
      asm volatile("s_waitcnt vmcnt(0)" ::: "memory");
    }
    __builtin_amdgcn_s_barrier();
    __builtin_amdgcn_sched_barrier(0);
    if (t + NBUF - 1 < nk) {
      int nb = cur + (NBUF - 1); if (nb >= NBUF) nb -= NBUF;
      stage(t + NBUF - 1, nb);
    }
    bf16x8 af[MFR], bf[4];
#pragma unroll
    for (int m = 0; m < MFR; m++)
      af[m] = *(const bf16x8*)(As + cur * 4 * PA + kgf * PA + (wr * (BM / 2) + m * 16 + fr) * 8);
#pragma unroll
    for (int n = 0; n < 4; n++)
      bf[n] = *(const bf16x8*)(Bs + cur * 4 * PB + kgf * PB + (wc * 64 + n * 16 + fr) * 8);
#pragma unroll
    for (int m = 0; m < MFR; m++)
#pragma unroll
      for (int n = 0; n < 4; n++)
        acc[m][n] = __builtin_amdgcn_mfma_f32_16x16x32_bf16(af[m], bf[n], acc[m][n], 0, 0, 0);
    cur = cur + 1; if (cur == NBUF) cur = 0;
  }

  const int r4 = (lane >> 4) * 4;
  float* co = (float*)Cout;
  bool addb = (EPI == 3);
  if constexpr (SPLITK == 2) {
    if (bz == 1) { co = (float*)Cout2; addb = false; }
  }
#pragma unroll
  for (int m = 0; m < MFR; m++) {
#pragma unroll
    for (int n = 0; n < 4; n++) {
      const int col = bcol + wc * 64 + n * 16 + fr;
      if constexpr (EPI == 5) {
        if (col < 1024) {
#pragma unroll
          for (int r = 0; r < 4; r++) {
            const int row = brow + wr * (BM / 2) + m * 16 + r4 + r;
            ((ushort*)Cout)[(size_t)row * 1024 + col] = f2bf(acc[m][n][r]);
          }
        } else {
          const int row0 = brow + wr * (BM / 2) + m * 16 + r4;
          ushort4 pk;
          pk.x = f2bf(acc[m][n][0]); pk.y = f2bf(acc[m][n][1]);
          pk.z = f2bf(acc[m][n][2]); pk.w = f2bf(acc[m][n][3]);
          *(ushort4*)((ushort*)Cout2 + (size_t)(col - 1024) * Msz + row0) = pk;
        }
      } else {
#pragma unroll
        for (int r = 0; r < 4; r++) {
          const int row = brow + wr * (BM / 2) + m * 16 + r4 + r;
          float val = acc[m][n][r];
          size_t o = (size_t)row * Nsz + col;
          if constexpr (EPI == 0) ((ushort*)Cout)[o] = f2bf(val);
          else if constexpr (EPI == 2) ((ushort*)Cout)[o] = f2bf(gelu_tanh(val + bias[col]));
          else co[o] = addb ? val + bias[col] : val;
        }
      }
    }
  }
}

template <int BM, int EPI, int SPLITK>
__global__ __launch_bounds__(256)
void gemm_kern(const ushort* __restrict__ A, const ushort* __restrict__ BT,
               void* __restrict__ Cout, void* __restrict__ Cout2,
               const float* __restrict__ bias, int Msz, int Nsz, int Ksz, int Kstride,
               int gx) {
  constexpr int NBUF = (BM == 64) ? 4 : 3;
  constexpr int PA = BM * 8 + 16, PB = 128 * 8 + 16;
  __shared__ __align__(16) ushort smem[NBUF * 4 * (PA + PB)];
  gemm_core<BM, EPI, SPLITK>(A, BT, Cout, Cout2, bias, Msz, Nsz, Ksz, Kstride,
                             gx, blockIdx.x, gridDim.x, smem);
}

// merged Q / KV / R projection: 256 + 640 + 80 = 976 blocks
__global__ __launch_bounds__(256)
void proj_gemm(const ushort* __restrict__ kvb, const ushort* __restrict__ WqT,
               const ushort* __restrict__ WkvT, const ushort* __restrict__ WrT,
               const ushort* __restrict__ remb,
               ushort* __restrict__ qb, ushort* __restrict__ kb,
               ushort* __restrict__ Vt, ushort* __restrict__ Rb) {
  __shared__ __align__(16) ushort smem[4 * 4 * (64 * 8 + 16 + 128 * 8 + 16)];
  const int bid = blockIdx.x;
  if (bid < 256) {
    gemm_core<64, 0, 1>(kvb + 512 * 1024, WqT, qb, nullptr, nullptr,
                        2048, 1024, 1024, 1024, 8, bid, 256, smem);
  } else if (bid < 896) {
    gemm_core<64, 5, 1>(kvb, WkvT, kb, Vt, nullptr,
                        2560, 2048, 1024, 1024, 16, bid - 256, 640, smem);
  } else {
    gemm_core<64, 0, 1>(remb, WrT, Rb, nullptr, nullptr,
                        640, 1024, 1024, 1024, 8, bid - 896, 80, smem);
  }
}

// ---------------- banded attention v5: split-KV, 8 waves/block ----------------
// Block: 64 queries x 1 head. wave = (qg, hf): qg = wave>>1 owns 16 queries,
// hf = wave&1 owns key-chunks [0..8] or [9..16]. States merged via LDS at the end.
__global__ __launch_bounds__(512)
void attn_mfma3(const ushort* __restrict__ qb, const ushort* __restrict__ kb,
                const ushort* __restrict__ Vt, const ushort* __restrict__ Rb,
                const float* __restrict__ ubias, const float* __restrict__ vbias,
                ushort* __restrict__ attb) {
  const int bid = blockIdx.x;
  const int swz = (bid & 7) * 64 + (bid >> 3);
  const int h = swz >> 5;
  const int i0 = (swz & 31) * 64;
  const int tid = threadIdx.x;
  const int wave = tid >> 6, lane = tid & 63;
  const int qg = wave >> 1, hf = wave & 1;
  const int g = lane >> 4, fr = lane & 15;
  const int hD = h * DH_;

  __shared__ __align__(16) ushort ring[8][16][64];
  __shared__ __align__(16) ushort Pl[8][16][40];
  __shared__ float obuf[4][16][68];
  __shared__ float mstM[4][16], mstL[4][16];

  const int qi = i0 + qg * 16 + fr;
  bf16x8 afu[2], afv[2];
#pragma unroll
  for (int kst = 0; kst < 2; kst++) {
    const int dof = kst * 32 + g * 8;
    bf16x8 qv = *(const bf16x8*)(qb + (size_t)qi * D_ + hD + dof);
    const float* up = ubias + hD + dof;
    const float* vp = vbias + hD + dof;
    bf16x8 au, av;
#pragma unroll
    for (int j = 0; j < 8; j++) {
      float q = bf2f((ushort)qv[j]);
      au[j] = (short)f2bf(q + up[j]);
      av[j] = (short)f2bf(q + vp[j]);
    }
    afu[kst] = au; afv[kst] = av;
  }

  const int jb = 256 + i0;
  const int smax = 2303 - i0;
  const int sbase = qg * 16;
  const int chS = hf ? 9 : 0;
  const int chE = hf ? 16 : 8;   // inclusive

  auto produce = [&](int r0, bf16x8 rf0, bf16x8 rf1) {
    f32x4 acc = {};
    acc = __builtin_amdgcn_mfma_f32_16x16x32_bf16(afv[0], rf0, acc, 0, 0, 0);
    acc = __builtin_amdgcn_mfma_f32_16x16x32_bf16(afv[1], rf1, acc, 0, 0, 0);
#pragma unroll
    for (int rr = 0; rr < 4; rr++)
      ring[wave][g * 4 + rr][(r0 + fr) & 63] = f2bf(acc[rr]);
  };
  auto loadRrow = [&](int row, bf16x8* out0, bf16x8* out1) {
    const int rc = row < 0 ? 0 : row;
    *out0 = *(const bf16x8*)(Rb + (size_t)rc * D_ + hD + g * 8);
    *out1 = *(const bf16x8*)(Rb + (size_t)rc * D_ + hD + 32 + g * 8);
  };
  auto loadK = [&](int ch, bf16x8 (&kp)[2][2]) {
#pragma unroll
    for (int half = 0; half < 2; half++) {
      const int sa = sbase + ch * 32 + half * 16 + fr;
      const int jc = (jb + sa < L_ - 1) ? (jb + sa) : (L_ - 1);
      kp[half][0] = *(const bf16x8*)(kb + (size_t)jc * 1024 + hD + g * 8);
      kp[half][1] = *(const bf16x8*)(kb + (size_t)jc * 1024 + hD + 32 + g * 8);
    }
  };
  auto loadV = [&](int ch, bf16x8 (&vp)[4]) {
    int kc = jb + sbase + ch * 32 + g * 8;
    if (kc > L_ - 8) kc = L_ - 8;
#pragma unroll
    for (int n = 0; n < 4; n++)
      vp[n] = *(const bf16x8*)(Vt + (size_t)(hD + n * 16 + fr) * L_ + kc);
  };

  // prologue ring: 3 tiles covering [480-chS*32, 527-chS*32]
  const int base = 480 - chS * 32;
#pragma unroll
  for (int t = 0; t < 3; t++) {
    const int r0 = base + t * 16;
    bf16x8 rf0, rf1;
    loadRrow(r0 + fr, &rf0, &rf1);
    produce(r0, rf0, rf1);
  }

  float m4[4], l4[4];
  f32x4 oacc[4] = {};
#pragma unroll
  for (int rr = 0; rr < 4; rr++) { m4[rr] = -1e30f; l4[rr] = 0.f; }

  bf16x8 kA[2][2], vA[4], kB[2][2], vB[4];
  bf16x8 rP0a, rP0b, rP1a, rP1b;
  loadK(chS, kA); loadV(chS, vA);

  auto body = [&](int ch, bf16x8 (&kU)[2][2], bf16x8 (&vU)[4],
                  bf16x8 (&kP)[2][2], bf16x8 (&vP)[4], bool first) -> bool {
    const int c0 = sbase + ch * 32;
    if (c0 > smax) return false;
    if (!first) {
      const int r0 = 480 - ch * 32;
      produce(r0, rP0a, rP0b);
      produce(r0 + 16, rP1a, rP1b);
    }
    if (ch < chE) {
      const int r0n = 480 - (ch + 1) * 32;
      loadRrow(r0n + fr, &rP0a, &rP0b);
      loadRrow(r0n + 16 + fr, &rP1a, &rP1b);
      loadK(ch + 1, kP);
      loadV(ch + 1, vP);
    }
    f32x4 sc[2];
#pragma unroll
    for (int half = 0; half < 2; half++) {
      f32x4 acc = {};
      acc = __builtin_amdgcn_mfma_f32_16x16x32_bf16(afu[0], kU[half][0], acc, 0, 0, 0);
      acc = __builtin_amdgcn_mfma_f32_16x16x32_bf16(afu[1], kU[half][1], acc, 0, 0, 0);
      const int rb2 = 512 + g * 4 - (ch * 32 + half * 16 + fr);
      const int sa = c0 + half * 16 + fr;
#pragma unroll
      for (int rr = 0; rr < 4; rr++) {
        const int r = rb2 + rr;
        const float bd = bf2f(ring[wave][g * 4 + rr][r & 63]);
        const bool valid = ((unsigned)r <= 512u) && (sa <= smax);
        sc[half][rr] = valid ? (acc[rr] + bd) * 0.125f : -1e30f;
      }
    }
    f32x4 cm;
#pragma unroll
    for (int rr = 0; rr < 4; rr++) cm[rr] = fmaxf(sc[0][rr], sc[1][rr]);
#pragma unroll
    for (int off = 8; off; off >>= 1)
#pragma unroll
      for (int rr = 0; rr < 4; rr++) cm[rr] = fmaxf(cm[rr], __shfl_xor(cm[rr], off));
    bool rise = (cm[0] > m4[0]) | (cm[1] > m4[1]) | (cm[2] > m4[2]) | (cm[3] > m4[3]);
    if (__any(rise)) {
#pragma unroll
      for (int rr = 0; rr < 4; rr++) {
        const float nm = fmaxf(m4[rr], cm[rr]);
        const float esc = __expf(m4[rr] - nm);
        m4[rr] = nm;
        l4[rr] *= esc;
#pragma unroll
        for (int n = 0; n < 4; n++) oacc[n][rr] *= esc;
      }
    }
    f32x4 pA, pB, rs;
#pragma unroll
    for (int rr = 0; rr < 4; rr++) {
      pA[rr] = __expf(sc[0][rr] - m4[rr]);
      pB[rr] = __expf(sc[1][rr] - m4[rr]);
      rs[rr] = pA[rr] + pB[rr];
    }
#pragma unroll
    for (int off = 8; off; off >>= 1)
#pragma unroll
      for (int rr = 0; rr < 4; rr++) rs[rr] += __shfl_xor(rs[rr], off);
#pragma unroll
    for (int rr = 0; rr < 4; rr++) l4[rr] += rs[rr];
#pragma unroll
    for (int rr = 0; rr < 4; rr++) {
      Pl[wave][g * 4 + rr][fr]      = f2bf(pA[rr]);
      Pl[wave][g * 4 + rr][16 + fr] = f2bf(pB[rr]);
    }
    bf16x8 pf = *(const bf16x8*)&Pl[wave][fr][g * 8];
#pragma unroll
    for (int n = 0; n < 4; n++)
      oacc[n] = __builtin_amdgcn_mfma_f32_16x16x32_bf16(pf, vU[n], oacc[n], 0, 0, 0);
    return true;
  };

  bool cont = body(chS, kA, vA, kB, vB, true);
  for (int ch = chS + 1; ch <= chE && cont; ch += 2) {
    cont = body(ch, kB, vB, kA, vA, false);
    if (!cont || ch + 1 > chE) break;
    cont = body(ch + 1, kA, vA, kB, vB, false);
  }

  // ---- merge the two kv-halves of each query group
  if (hf == 1) {
    if (fr == 0) {
#pragma unroll
      for (int rr = 0; rr < 4; rr++) {
        mstM[qg][g * 4 + rr] = m4[rr];
        mstL[qg][g * 4 + rr] = l4[rr];
      }
    }
#pragma unroll
    for (int rr = 0; rr < 4; rr++)
#pragma unroll
      for (int n = 0; n < 4; n++)
        obuf[qg][g * 4 + rr][n * 16 + fr] = oacc[n][rr];
  }
  __syncthreads();
  if (hf == 0) {
#pragma unroll
    for (int rr = 0; rr < 4; rr++) {
      const float mB = mstM[qg][g * 4 + rr];
      const float lB = mstL[qg][g * 4 + rr];
      const float m = fmaxf(m4[rr], mB);
      const float eA = __expf(m4[rr] - m);
      const float eB = __expf(mB - m);
      const float inv = 1.f / (l4[rr] * eA + lB * eB);
      const size_t rowo = (size_t)(i0 + sbase + g * 4 + rr) * D_ + hD;
#pragma unroll
      for (int n = 0; n < 4; n++) {
        const float o = oacc[n][rr] * eA + obuf[qg][g * 4 + rr][n * 16 + fr] * eB;
        attb[rowo + n * 16 + fr] = f2bf(o * inv);
      }
    }
  }
}

// ---------------- residual + LayerNorm (2 or 3 addends) ----------------
__global__ __launch_bounds__(256)
void ln_kernel(const float* __restrict__ a, const float* __restrict__ b,
               const float* __restrict__ c,
               const float* __restrict__ gamma, const float* __restrict__ beta,
               float* __restrict__ outf, ushort* __restrict__ outb) {
  const int row = blockIdx.x;
  const int tid = threadIdx.x;
  const int wave = tid >> 6, lane = tid & 63;
  float4 va = ((const float4*)(a + (size_t)row * D_))[tid];
  float4 vb4 = ((const float4*)(b + (size_t)row * D_))[tid];
  float4 xv;
  xv.x = va.x + vb4.x; xv.y = va.y + vb4.y; xv.z = va.z + vb4.z; xv.w = va.w + vb4.w;
  if (c) {
    float4 vc = ((const float4*)(c + (size_t)row * D_))[tid];
    xv.x += vc.x; xv.y += vc.y; xv.z += vc.z; xv.w += vc.w;
  }
  float s = xv.x + xv.y + xv.z + xv.w;
  float q = xv.x * xv.x + xv.y * xv.y + xv.z * xv.z + xv.w * xv.w;
#pragma unroll
  for (int off = 32; off; off >>= 1) { s += __shfl_xor(s, off); q += __shfl_xor(q, off); }
  __shared__ float red[8];
  if (lane == 0) { red[wave * 2] = s; red[wave * 2 + 1] = q; }
  __syncthreads();
  float ts = red[0] + red[2] + red[4] + red[6];
  float tq = red[1] + red[3] + red[5] + red[7];
  float mu = ts * (1.f / D_);
  float var = tq * (1.f / D_) - mu * mu;
  float rs = rsqrtf(var + 1e-5f);
  float4 g4 = ((const float4*)gamma)[tid];
  float4 be4 = ((const float4*)beta)[tid];
  float4 y;
  y.x = (xv.x - mu) * rs * g4.x + be4.x;
  y.y = (xv.y - mu) * rs * g4.y + be4.y;
  y.z = (xv.z - mu) * rs * g4.z + be4.z;
  y.w = (xv.w - mu) * rs * g4.w + be4.w;
  ((float4*)(outf + (size_t)row * D_))[tid] = y;
  if (outb) ((ushort4*)(outb + (size_t)row * D_))[tid] = pack4(y);
}

extern "C" void kernel_launch(void* const* d_in, const int* in_sizes, int n_in,
                              void* d_out, int out_size, void* d_ws, size_t ws_size,
                              hipStream_t stream) {
  const float* x    = (const float*)d_in[0];
  const float* mem  = (const float*)d_in[1];
  const float* Wq   = (const float*)d_in[2];
  const float* Wk   = (const float*)d_in[3];
  const float* Wv   = (const float*)d_in[4];
  const float* Wo   = (const float*)d_in[5];
  const float* Wr   = (const float*)d_in[6];
  const float* u    = (const float*)d_in[7];
  const float* v    = (const float*)d_in[8];
  const float* ln1g = (const float*)d_in[9];
  const float* ln1b = (const float*)d_in[10];
  const float* W1   = (const float*)d_in[11];
  const float* b1   = (const float*)d_in[12];
  const float* W2   = (const float*)d_in[13];
  const float* b2   = (const float*)d_in[14];
  const float* ln2g = (const float*)d_in[15];
  const float* ln2b = (const float*)d_in[16];
  float* out = (float*)d_out;

  char* ws = (char*)d_ws;
  size_t off = 0;
  auto take = [&](size_t n) { char* p = ws + off; off += (n + 255) & ~(size_t)255; return p; };

  ushort* WqT = (ushort*)take(2097152);
  ushort* WkT = (ushort*)take(2097152);   // WkT||WvT contiguous = [2048][1024]
  ushort* WvT = (ushort*)take(2097152);
  ushort* WoT = (ushort*)take(2097152);
  ushort* WrT = (ushort*)take(2097152);
  ushort* W1T = (ushort*)take(8388608);   // [4096][1024]
  ushort* W2T = (ushort*)take(8388608);   // [1024][4096]

  char* regA = take(8388608);             // kvb + remb; later reused for fbuf
  ushort* kvb  = (ushort*)regA;
  ushort* remb = (ushort*)(regA + 5242880);
  float*  fbuf = (float*)regA;

  char* regB = take(20185088);            // qb,kb,Vt,Rb,attb; overlays: o2b, g
  ushort* qb   = (ushort*)regB;
  ushort* kb   = (ushort*)(regB + 4194304);
  ushort* Vt   = (ushort*)(regB + 9437184);           // [1024][2560]
  ushort* Rb   = (ushort*)(regB + 14680064);
  ushort* attb = (ushort*)(regB + 15990784);
  float*  o2b  = (float*)regB;
  ushort* g    = (ushort*)regB;

  float*  o2 = (float*)take(8388608);
  float*  h  = (float*)take(8388608);
  ushort* hb = (ushort*)take(4194304);

  prep_kernel<<<17152, 256, 0, stream>>>(x, mem, Wq, Wk, Wv, Wo, Wr, W1, W2,
                                         WqT, WkT, WvT, WoT, WrT, W1T, W2T, kvb, remb);

  proj_gemm<<<976, 256, 0, stream>>>(kvb, WqT, WkT, WrT, remb, qb, kb, Vt, Rb);

  attn_mfma3<<<512, 512, 0, stream>>>(qb, kb, Vt, Rb, u, v, attb);

  gemm_kern<64, 1, 2><<<512, 256, 0, stream>>>(attb, WoT, o2, o2b, nullptr,
                                               2048, 1024, 512, 1024, 8);
  ln_kernel<<<2048, 256, 0, stream>>>(x, o2, o2b, ln1g, ln1b, h, hb);
  gemm_kern<128, 2, 1><<<512, 256, 0, stream>>>(hb, W1T, g, nullptr, b1,
                                                2048, 4096, 1024, 1024, 32);
  gemm_kern<64, 3, 2><<<512, 256, 0, stream>>>(g, W2T, fbuf, o2, b2,
                                               2048, 1024, 2048, 4096, 8);
  ln_kernel<<<2048, 256, 0, stream>>>(h, fbuf, o2, ln2g, ln2b, out, nullptr);
}

// Round 7
// 248.504 us; speedup vs baseline: 1.0310x; 1.0310x over previous
//
#include <hip/hip_runtime.h>
#include <hip/hip_bf16.h>
#include <cstdint>

#define S_ 2048
#define M_ 512
#define L_ 2560
#define D_ 1024
#define F_ 4096
#define H_ 16
#define DH_ 64
#define W_ 256
#define NR_ 513
#define NRP_ 640

typedef unsigned int uint32;
typedef __attribute__((ext_vector_type(8))) short bf16x8;
typedef __attribute__((ext_vector_type(4))) float f32x4;

__device__ __forceinline__ ushort f2bf(float f) {
  uint32 u = __builtin_bit_cast(uint32, f);
  u += 0x7FFFu + ((u >> 16) & 1u);
  return (ushort)(u >> 16);
}
__device__ __forceinline__ float bf2f(ushort s) {
  uint32 u = ((uint32)s) << 16;
  return __builtin_bit_cast(float, u);
}
__device__ __forceinline__ ushort4 pack4(float4 vf) {
  ushort4 r;
  r.x = f2bf(vf.x); r.y = f2bf(vf.y); r.z = f2bf(vf.z); r.w = f2bf(vf.w);
  return r;
}
__device__ __forceinline__ float gelu_tanh(float x) {
  float t = 0.7978845608028654f * x * (1.f + 0.044715f * x * x);
  float e = __expf(2.f * t);
  float th = 1.f - 2.f / (e + 1.f);
  return 0.5f * x * (1.f + th);
}

// async global(16B/lane) -> LDS, wave-uniform LDS base + lane*16
__device__ __forceinline__ void gld_lds16(const ushort* g, ushort* l) {
  __builtin_amdgcn_global_load_lds((const __attribute__((address_space(1))) void*)g,
                                   (__attribute__((address_space(3))) void*)l, 16, 0, 0);
}

// ================= fused prep: 7 weight transposes + kv pack + sinusoid =================
__device__ __forceinline__ void tr_tile(const float* __restrict__ in, ushort* __restrict__ out,
                                        int R, int C, int c0, int r0, int tx, int ty,
                                        float (*tile)[33]) {
#pragma unroll
  for (int i = 0; i < 4; i++)
    tile[ty + i * 8][tx] = in[(size_t)(r0 + ty + i * 8) * C + c0 + tx];
  __syncthreads();
#pragma unroll
  for (int i = 0; i < 4; i++)
    out[(size_t)(c0 + ty + i * 8) * R + r0 + tx] = f2bf(tile[tx][ty + i * 8]);
}

__global__ __launch_bounds__(256)
void prep_kernel(const float* __restrict__ x, const float* __restrict__ mem,
                 const float* __restrict__ Wq, const float* __restrict__ Wk,
                 const float* __restrict__ Wv, const float* __restrict__ Wo,
                 const float* __restrict__ Wr, const float* __restrict__ W1,
                 const float* __restrict__ W2,
                 ushort* __restrict__ WqT, ushort* __restrict__ WkT,
                 ushort* __restrict__ WvT, ushort* __restrict__ WoT,
                 ushort* __restrict__ WrT, ushort* __restrict__ W1T,
                 ushort* __restrict__ W2T,
                 ushort* __restrict__ kvb, ushort* __restrict__ remb) {
  __shared__ float tile[32][33];
  const int bid = blockIdx.x;
  const int tid = threadIdx.x;
  const int tx = tid & 31, ty = tid >> 5;

  if (bid < 5120) {
    const int which = bid >> 10, idx = bid & 1023;
    const float* ins[5] = {Wq, Wk, Wv, Wo, Wr};
    ushort* outs[5] = {WqT, WkT, WvT, WoT, WrT};
    tr_tile(ins[which], outs[which], 1024, 1024, (idx & 31) * 32, (idx >> 5) * 32, tx, ty, tile);
  } else if (bid < 9216) {
    const int idx = bid - 5120;
    tr_tile(W1, W1T, 1024, 4096, (idx % 128) * 32, (idx / 128) * 32, tx, ty, tile);
  } else if (bid < 13312) {
    const int idx = bid - 9216;
    tr_tile(W2, W2T, 4096, 1024, (idx & 31) * 32, (idx >> 5) * 32, tx, ty, tile);
  } else if (bid < 15872) {
    const int k = (bid - 13312) * 256 + tid;
    const int l = k >> 8, c = k & 255;
    const float4* src = (l < M_) ? (const float4*)(mem + (size_t)l * D_)
                                 : (const float4*)(x + (size_t)(l - M_) * D_);
    ((ushort4*)kvb)[k] = pack4(src[c]);
  } else {
    const int idx = (bid - 15872) * 256 + tid;
    const int r = idx >> 9, f = idx & 511;
    if (r < NR_) {
      float invf = expf(-(float)f * (9.210340371976184f / 512.0f));
      float ang = (float)(r - W_) * invf;
      remb[(size_t)r * D_ + f] = f2bf(sinf(ang));
      remb[(size_t)r * D_ + 512 + f] = f2bf(cosf(ang));
    } else if (r < NRP_) {
      remb[(size_t)r * D_ + f] = 0;
      remb[(size_t)r * D_ + 512 + f] = 0;
    }
  }
}

// ================= MFMA GEMM core: gload_lds + NBUF-deep LDS ring, counted vmcnt ======
template <int BM, int EPI, int SPLITK>
__device__ __forceinline__
void gemm_core(const ushort* __restrict__ A, const ushort* __restrict__ BT,
               void* __restrict__ Cout, void* __restrict__ Cout2,
               const float* __restrict__ bias, int Msz, int Nsz, int Ksz, int Kstride,
               int gx, int bid, int nwg, ushort* smem) {
  constexpr int PA = BM * 8 + 16;
  constexpr int PB = 128 * 8 + 16;
  constexpr int MFR = BM / 32;
  constexpr int NA = BM / 64;
  constexpr int NBUF = (BM == 64) ? 4 : 3;
  const int tid = threadIdx.x;
  const int wave = tid >> 6, lane = tid & 63;
  const int wr = wave >> 1, wc = wave & 1;

  const int q = nwg >> 3;
  const int swz = (bid & 7) * q + (bid >> 3);
  const int gy = Msz / BM;
  const int bx = swz % gx;
  const int rest = swz / gx;
  const int by = rest % gy;
  const int bz = rest / gy;

  const int brow = by * BM, bcol = bx * 128;
  const int koff = (SPLITK == 2) ? bz * Ksz : 0;

  ushort* As = smem;
  ushort* Bs = smem + NBUF * 4 * PA;

  const ushort* ag[NA]; int alo[NA];
#pragma unroll
  for (int i = 0; i < NA; i++) {
    int li = i * 4 + wave;
    int kg, rowbase;
    if constexpr (BM == 128) { kg = li >> 1; rowbase = (li & 1) * 64; }
    else { kg = li; rowbase = 0; }
    ag[i] = A + (size_t)(brow + rowbase + lane) * Kstride + koff + kg * 8;
    alo[i] = kg * PA + rowbase * 8;
  }
  const ushort* bg[2]; int blo[2];
#pragma unroll
  for (int i = 0; i < 2; i++) {
    int li = i * 4 + wave;
    int kg = li >> 1, rowbase = (li & 1) * 64;
    bg[i] = BT + (size_t)(bcol + rowbase + lane) * Kstride + koff + kg * 8;
    blo[i] = kg * PB + rowbase * 8;
  }

  f32x4 acc[MFR][4] = {};
  const int kgf = lane >> 4, fr = lane & 15;
  const int nk = Ksz >> 5;

  auto stage = [&](int t, int buf) {
    const int ko = t * 32;
    ushort* ab = As + buf * 4 * PA;
    ushort* bb = Bs + buf * 4 * PB;
#pragma unroll
    for (int i = 0; i < NA; i++) gld_lds16(ag[i] + ko, ab + alo[i]);
#pragma unroll
    for (int i = 0; i < 2; i++) gld_lds16(bg[i] + ko, bb + blo[i]);
  };

#pragma unroll
  for (int i = 0; i < NBUF - 1; i++) stage(i, i);

  int cur = 0;
  for (int t = 0; t < nk; t++) {
    if (t + NBUF - 2 < nk) {
      if constexpr (NBUF == 4) asm volatile("s_waitcnt vmcnt(6)" ::: "memory");
      else asm volatile("s_waitcnt vmcnt(4)" ::: "memory");
    } else {
      asm volatile("s_waitcnt vmcnt(0)" ::: "memory");
    }
    __builtin_amdgcn_s_barrier();
    __builtin_amdgcn_sched_barrier(0);
    if (t + NBUF - 1 < nk) {
      int nb = cur + (NBUF - 1); if (nb >= NBUF) nb -= NBUF;
      stage(t + NBUF - 1, nb);
    }
    bf16x8 af[MFR], bf[4];
#pragma unroll
    for (int m = 0; m < MFR; m++)
      af[m] = *(const bf16x8*)(As + cur * 4 * PA + kgf * PA + (wr * (BM / 2) + m * 16 + fr) * 8);
#pragma unroll
    for (int n = 0; n < 4; n++)
      bf[n] = *(const bf16x8*)(Bs + cur * 4 * PB + kgf * PB + (wc * 64 + n * 16 + fr) * 8);
#pragma unroll
    for (int m = 0; m < MFR; m++)
#pragma unroll
      for (int n = 0; n < 4; n++)
        acc[m][n] = __builtin_amdgcn_mfma_f32_16x16x32_bf16(af[m], bf[n], acc[m][n], 0, 0, 0);
    cur = cur + 1; if (cur == NBUF) cur = 0;
  }

  const int r4 = (lane >> 4) * 4;
  float* co = (float*)Cout;
  bool addb = (EPI == 3);
  if constexpr (SPLITK == 2) {
    if (bz == 1) { co = (float*)Cout2; addb = false; }
  }
#pragma unroll
  for (int m = 0; m < MFR; m++) {
#pragma unroll
    for (int n = 0; n < 4; n++) {
      const int col = bcol + wc * 64 + n * 16 + fr;
      if constexpr (EPI == 5) {
        if (col < 1024) {
#pragma unroll
          for (int r = 0; r < 4; r++) {
            const int row = brow + wr * (BM / 2) + m * 16 + r4 + r;
            ((ushort*)Cout)[(size_t)row * 1024 + col] = f2bf(acc[m][n][r]);
          }
        } else {
          const int row0 = brow + wr * (BM / 2) + m * 16 + r4;
          ushort4 pk;
          pk.x = f2bf(acc[m][n][0]); pk.y = f2bf(acc[m][n][1]);
          pk.z = f2bf(acc[m][n][2]); pk.w = f2bf(acc[m][n][3]);
          *(ushort4*)((ushort*)Cout2 + (size_t)(col - 1024) * Msz + row0) = pk;
        }
      } else {
#pragma unroll
        for (int r = 0; r < 4; r++) {
          const int row = brow + wr * (BM / 2) + m * 16 + r4 + r;
          float val = acc[m][n][r];
          size_t o = (size_t)row * Nsz + col;
          if constexpr (EPI == 0) ((ushort*)Cout)[o] = f2bf(val);
          else if constexpr (EPI == 2) ((ushort*)Cout)[o] = f2bf(gelu_tanh(val + bias[col]));
          else co[o] = addb ? val + bias[col] : val;
        }
      }
    }
  }
}

template <int BM, int EPI, int SPLITK>
__global__ __launch_bounds__(256)
void gemm_kern(const ushort* __restrict__ A, const ushort* __restrict__ BT,
               void* __restrict__ Cout, void* __restrict__ Cout2,
               const float* __restrict__ bias, int Msz, int Nsz, int Ksz, int Kstride,
               int gx) {
  constexpr int NBUF = (BM == 64) ? 4 : 3;
  constexpr int PA = BM * 8 + 16, PB = 128 * 8 + 16;
  __shared__ __align__(16) ushort smem[NBUF * 4 * (PA + PB)];
  gemm_core<BM, EPI, SPLITK>(A, BT, Cout, Cout2, bias, Msz, Nsz, Ksz, Kstride,
                             gx, blockIdx.x, gridDim.x, smem);
}

// merged Q / KV / R projection: 256 + 640 + 80 = 976 blocks
__global__ __launch_bounds__(256)
void proj_gemm(const ushort* __restrict__ kvb, const ushort* __restrict__ WqT,
               const ushort* __restrict__ WkvT, const ushort* __restrict__ WrT,
               const ushort* __restrict__ remb,
               ushort* __restrict__ qb, ushort* __restrict__ kb,
               ushort* __restrict__ Vt, ushort* __restrict__ Rb) {
  __shared__ __align__(16) ushort smem[4 * 4 * (64 * 8 + 16 + 128 * 8 + 16)];
  const int bid = blockIdx.x;
  if (bid < 256) {
    gemm_core<64, 0, 1>(kvb + 512 * 1024, WqT, qb, nullptr, nullptr,
                        2048, 1024, 1024, 1024, 8, bid, 256, smem);
  } else if (bid < 896) {
    gemm_core<64, 5, 1>(kvb, WkvT, kb, Vt, nullptr,
                        2560, 2048, 1024, 1024, 16, bid - 256, 640, smem);
  } else {
    gemm_core<64, 0, 1>(remb, WrT, Rb, nullptr, nullptr,
                        640, 1024, 1024, 1024, 8, bid - 896, 80, smem);
  }
}

// ---------------- banded attention v6: lazy-max, per-lane partial l, setprio ----------
// Block: 64 queries x 1 head, 4 waves x 16 queries (r5 structure).
// Lazy softmax: row-uniform m established on chunk 0; after that only a per-lane
// rise check (sc > m+8). P bounded by e^8; l kept as per-lane partial, reduced once.
__global__ __launch_bounds__(256)
void attn_mfma4(const ushort* __restrict__ qb, const ushort* __restrict__ kb,
                const ushort* __restrict__ Vt, const ushort* __restrict__ Rb,
                const float* __restrict__ ubias, const float* __restrict__ vbias,
                ushort* __restrict__ attb) {
  const int bid = blockIdx.x;
  const int swz = (bid & 7) * 64 + (bid >> 3);
  const int h = swz >> 5;
  const int i0 = (swz & 31) * 64;
  const int tid = threadIdx.x;
  const int wave = tid >> 6, lane = tid & 63;
  const int g = lane >> 4, fr = lane & 15;
  const int hD = h * DH_;

  __shared__ __align__(16) ushort ring[4][16][64];
  __shared__ __align__(16) ushort Pl[4][16][40];

  const int qi = i0 + wave * 16 + fr;
  bf16x8 afu[2], afv[2];
#pragma unroll
  for (int kst = 0; kst < 2; kst++) {
    const int dof = kst * 32 + g * 8;
    bf16x8 qv = *(const bf16x8*)(qb + (size_t)qi * D_ + hD + dof);
    const float* up = ubias + hD + dof;
    const float* vp = vbias + hD + dof;
    bf16x8 au, av;
#pragma unroll
    for (int j = 0; j < 8; j++) {
      float q = bf2f((ushort)qv[j]);
      au[j] = (short)f2bf(q + up[j]);
      av[j] = (short)f2bf(q + vp[j]);
    }
    afu[kst] = au; afv[kst] = av;
  }

  const int jb = 256 + i0;
  const int smax = 2303 - i0;
  const int sbase = wave * 16;

  auto produce = [&](int r0, bf16x8 rf0, bf16x8 rf1) {
    f32x4 acc = {};
    __builtin_amdgcn_s_setprio(1);
    acc = __builtin_amdgcn_mfma_f32_16x16x32_bf16(afv[0], rf0, acc, 0, 0, 0);
    acc = __builtin_amdgcn_mfma_f32_16x16x32_bf16(afv[1], rf1, acc, 0, 0, 0);
    __builtin_amdgcn_s_setprio(0);
#pragma unroll
    for (int rr = 0; rr < 4; rr++)
      ring[wave][g * 4 + rr][(r0 + fr) & 63] = f2bf(acc[rr]);
  };
  auto loadRrow = [&](int row, bf16x8* out0, bf16x8* out1) {
    const int rc = row < 0 ? 0 : row;
    *out0 = *(const bf16x8*)(Rb + (size_t)rc * D_ + hD + g * 8);
    *out1 = *(const bf16x8*)(Rb + (size_t)rc * D_ + hD + 32 + g * 8);
  };
  auto loadK = [&](int ch, bf16x8 (&kp)[2][2]) {
#pragma unroll
    for (int half = 0; half < 2; half++) {
      const int sa = sbase + ch * 32 + half * 16 + fr;
      const int jc = (jb + sa < L_ - 1) ? (jb + sa) : (L_ - 1);
      kp[half][0] = *(const bf16x8*)(kb + (size_t)jc * 1024 + hD + g * 8);
      kp[half][1] = *(const bf16x8*)(kb + (size_t)jc * 1024 + hD + 32 + g * 8);
    }
  };
  auto loadV = [&](int ch, bf16x8 (&vp)[4]) {
    int kc = jb + sbase + ch * 32 + g * 8;
    if (kc > L_ - 8) kc = L_ - 8;
#pragma unroll
    for (int n = 0; n < 4; n++)
      vp[n] = *(const bf16x8*)(Vt + (size_t)(hD + n * 16 + fr) * L_ + kc);
  };

#pragma unroll
  for (int t = 0; t < 3; t++) {
    const int r0 = 480 + t * 16;
    bf16x8 rf0, rf1;
    loadRrow(r0 + fr, &rf0, &rf1);
    produce(r0, rf0, rf1);
  }

  float m4[4], l4[4];
  f32x4 oacc[4] = {};
#pragma unroll
  for (int rr = 0; rr < 4; rr++) { m4[rr] = -1e30f; l4[rr] = 0.f; }

  bf16x8 kA[2][2], vA[4], kB[2][2], vB[4];
  bf16x8 rP0a, rP0b, rP1a, rP1b;
  loadK(0, kA); loadV(0, vA);

  auto body = [&](int ch, bf16x8 (&kU)[2][2], bf16x8 (&vU)[4],
                  bf16x8 (&kP)[2][2], bf16x8 (&vP)[4], bool first) -> bool {
    const int c0 = sbase + ch * 32;
    if (c0 > smax) return false;
    if (!first) {
      const int r0 = 480 - ch * 32;
      produce(r0, rP0a, rP0b);
      produce(r0 + 16, rP1a, rP1b);
    }
    if (ch < 16) {
      const int r0n = 480 - (ch + 1) * 32;
      loadRrow(r0n + fr, &rP0a, &rP0b);
      loadRrow(r0n + 16 + fr, &rP1a, &rP1b);
      loadK(ch + 1, kP);
      loadV(ch + 1, vP);
    }
    f32x4 sc[2];
#pragma unroll
    for (int half = 0; half < 2; half++) {
      f32x4 acc = {};
      __builtin_amdgcn_s_setprio(1);
      acc = __builtin_amdgcn_mfma_f32_16x16x32_bf16(afu[0], kU[half][0], acc, 0, 0, 0);
      acc = __builtin_amdgcn_mfma_f32_16x16x32_bf16(afu[1], kU[half][1], acc, 0, 0, 0);
      __builtin_amdgcn_s_setprio(0);
      const int rb2 = 512 + g * 4 - (ch * 32 + half * 16 + fr);
      const int sa = c0 + half * 16 + fr;
#pragma unroll
      for (int rr = 0; rr < 4; rr++) {
        const int r = rb2 + rr;
        const float bd = bf2f(ring[wave][g * 4 + rr][r & 63]);
        const bool valid = ((unsigned)r <= 512u) && (sa <= smax);
        sc[half][rr] = valid ? (acc[rr] + bd) * 0.125f : -1e30f;
      }
    }
    if (first) {
      // establish row-uniform m (once per wave)
      f32x4 cm;
#pragma unroll
      for (int rr = 0; rr < 4; rr++) cm[rr] = fmaxf(sc[0][rr], sc[1][rr]);
#pragma unroll
      for (int off = 8; off; off >>= 1)
#pragma unroll
        for (int rr = 0; rr < 4; rr++) cm[rr] = fmaxf(cm[rr], __shfl_xor(cm[rr], off));
#pragma unroll
      for (int rr = 0; rr < 4; rr++) m4[rr] = cm[rr];
    } else {
      // lazy rise check: no shuffles in the common path
      bool rise = false;
#pragma unroll
      for (int rr = 0; rr < 4; rr++)
        rise |= (fmaxf(sc[0][rr], sc[1][rr]) > m4[rr] + 8.f);
      if (__any(rise)) {
        f32x4 cm;
#pragma unroll
        for (int rr = 0; rr < 4; rr++) cm[rr] = fmaxf(sc[0][rr], sc[1][rr]);
#pragma unroll
        for (int off = 8; off; off >>= 1)
#pragma unroll
          for (int rr = 0; rr < 4; rr++) cm[rr] = fmaxf(cm[rr], __shfl_xor(cm[rr], off));
#pragma unroll
        for (int rr = 0; rr < 4; rr++) {
          const float nm = fmaxf(m4[rr], cm[rr]);
          const float esc = __expf(m4[rr] - nm);
          m4[rr] = nm;
          l4[rr] *= esc;
#pragma unroll
          for (int n = 0; n < 4; n++) oacc[n][rr] *= esc;
        }
      }
    }
    f32x4 pA, pB;
#pragma unroll
    for (int rr = 0; rr < 4; rr++) {
      pA[rr] = __expf(sc[0][rr] - m4[rr]);
      pB[rr] = __expf(sc[1][rr] - m4[rr]);
      l4[rr] += pA[rr] + pB[rr];          // per-lane partial denominator
    }
#pragma unroll
    for (int rr = 0; rr < 4; rr++) {
      Pl[wave][g * 4 + rr][fr]      = f2bf(pA[rr]);
      Pl[wave][g * 4 + rr][16 + fr] = f2bf(pB[rr]);
    }
    bf16x8 pf = *(const bf16x8*)&Pl[wave][fr][g * 8];
    __builtin_amdgcn_s_setprio(1);
#pragma unroll
    for (int n = 0; n < 4; n++)
      oacc[n] = __builtin_amdgcn_mfma_f32_16x16x32_bf16(pf, vU[n], oacc[n], 0, 0, 0);
    __builtin_amdgcn_s_setprio(0);
    return true;
  };

  bool cont = body(0, kA, vA, kB, vB, true);
  for (int ch = 1; ch < 17 && cont; ch += 2) {
    cont = body(ch, kB, vB, kA, vA, false);
    if (!cont || ch + 1 >= 17) break;
    cont = body(ch + 1, kA, vA, kB, vB, false);
  }

  // epilogue: single denominator reduction, then write
#pragma unroll
  for (int off = 8; off; off >>= 1)
#pragma unroll
    for (int rr = 0; rr < 4; rr++) l4[rr] += __shfl_xor(l4[rr], off);
#pragma unroll
  for (int rr = 0; rr < 4; rr++) {
    const float inv = 1.f / l4[rr];
    const size_t rowo = (size_t)(i0 + sbase + g * 4 + rr) * D_ + hD;
#pragma unroll
    for (int n = 0; n < 4; n++)
      attb[rowo + n * 16 + fr] = f2bf(oacc[n][rr] * inv);
  }
}

// ---------------- residual + LayerNorm (2 or 3 addends) ----------------
__global__ __launch_bounds__(256)
void ln_kernel(const float* __restrict__ a, const float* __restrict__ b,
               const float* __restrict__ c,
               const float* __restrict__ gamma, const float* __restrict__ beta,
               float* __restrict__ outf, ushort* __restrict__ outb) {
  const int row = blockIdx.x;
  const int tid = threadIdx.x;
  const int wave = tid >> 6, lane = tid & 63;
  float4 va = ((const float4*)(a + (size_t)row * D_))[tid];
  float4 vb4 = ((const float4*)(b + (size_t)row * D_))[tid];
  float4 xv;
  xv.x = va.x + vb4.x; xv.y = va.y + vb4.y; xv.z = va.z + vb4.z; xv.w = va.w + vb4.w;
  if (c) {
    float4 vc = ((const float4*)(c + (size_t)row * D_))[tid];
    xv.x += vc.x; xv.y += vc.y; xv.z += vc.z; xv.w += vc.w;
  }
  float s = xv.x + xv.y + xv.z + xv.w;
  float q = xv.x * xv.x + xv.y * xv.y + xv.z * xv.z + xv.w * xv.w;
#pragma unroll
  for (int off = 32; off; off >>= 1) { s += __shfl_xor(s, off); q += __shfl_xor(q, off); }
  __shared__ float red[8];
  if (lane == 0) { red[wave * 2] = s; red[wave * 2 + 1] = q; }
  __syncthreads();
  float ts = red[0] + red[2] + red[4] + red[6];
  float tq = red[1] + red[3] + red[5] + red[7];
  float mu = ts * (1.f / D_);
  float var = tq * (1.f / D_) - mu * mu;
  float rs = rsqrtf(var + 1e-5f);
  float4 g4 = ((const float4*)gamma)[tid];
  float4 be4 = ((const float4*)beta)[tid];
  float4 y;
  y.x = (xv.x - mu) * rs * g4.x + be4.x;
  y.y = (xv.y - mu) * rs * g4.y + be4.y;
  y.z = (xv.z - mu) * rs * g4.z + be4.z;
  y.w = (xv.w - mu) * rs * g4.w + be4.w;
  ((float4*)(outf + (size_t)row * D_))[tid] = y;
  if (outb) ((ushort4*)(outb + (size_t)row * D_))[tid] = pack4(y);
}

extern "C" void kernel_launch(void* const* d_in, const int* in_sizes, int n_in,
                              void* d_out, int out_size, void* d_ws, size_t ws_size,
                              hipStream_t stream) {
  const float* x    = (const float*)d_in[0];
  const float* mem  = (const float*)d_in[1];
  const float* Wq   = (const float*)d_in[2];
  const float* Wk   = (const float*)d_in[3];
  const float* Wv   = (const float*)d_in[4];
  const float* Wo   = (const float*)d_in[5];
  const float* Wr   = (const float*)d_in[6];
  const float* u    = (const float*)d_in[7];
  const float* v    = (const float*)d_in[8];
  const float* ln1g = (const float*)d_in[9];
  const float* ln1b = (const float*)d_in[10];
  const float* W1   = (const float*)d_in[11];
  const float* b1   = (const float*)d_in[12];
  const float* W2   = (const float*)d_in[13];
  const float* b2   = (const float*)d_in[14];
  const float* ln2g = (const float*)d_in[15];
  const float* ln2b = (const float*)d_in[16];
  float* out = (float*)d_out;

  char* ws = (char*)d_ws;
  size_t off = 0;
  auto take = [&](size_t n) { char* p = ws + off; off += (n + 255) & ~(size_t)255; return p; };

  ushort* WqT = (ushort*)take(2097152);
  ushort* WkT = (ushort*)take(2097152);   // WkT||WvT contiguous = [2048][1024]
  ushort* WvT = (ushort*)take(2097152);
  ushort* WoT = (ushort*)take(2097152);
  ushort* WrT = (ushort*)take(2097152);
  ushort* W1T = (ushort*)take(8388608);   // [4096][1024]
  ushort* W2T = (ushort*)take(8388608);   // [1024][4096]

  char* regA = take(8388608);             // kvb + remb; later reused for fbuf
  ushort* kvb  = (ushort*)regA;
  ushort* remb = (ushort*)(regA + 5242880);
  float*  fbuf = (float*)regA;

  char* regB = take(20185088);            // qb,kb,Vt,Rb,attb; overlays: o2b, g
  ushort* qb   = (ushort*)regB;
  ushort* kb   = (ushort*)(regB + 4194304);
  ushort* Vt   = (ushort*)(regB + 9437184);           // [1024][2560]
  ushort* Rb   = (ushort*)(regB + 14680064);
  ushort* attb = (ushort*)(regB + 15990784);
  float*  o2b  = (float*)regB;
  ushort* g    = (ushort*)regB;

  float*  o2 = (float*)take(8388608);
  float*  h  = (float*)take(8388608);
  ushort* hb = (ushort*)take(4194304);

  prep_kernel<<<17152, 256, 0, stream>>>(x, mem, Wq, Wk, Wv, Wo, Wr, W1, W2,
                                         WqT, WkT, WvT, WoT, WrT, W1T, W2T, kvb, remb);

  proj_gemm<<<976, 256, 0, stream>>>(kvb, WqT, WkT, WrT, remb, qb, kb, Vt, Rb);

  attn_mfma4<<<512, 256, 0, stream>>>(qb, kb, Vt, Rb, u, v, attb);

  gemm_kern<64, 1, 2><<<512, 256, 0, stream>>>(attb, WoT, o2, o2b, nullptr,
                                               2048, 1024, 512, 1024, 8);
  ln_kernel<<<2048, 256, 0, stream>>>(x, o2, o2b, ln1g, ln1b, h, hb);
  gemm_kern<128, 2, 1><<<512, 256, 0, stream>>>(hb, W1T, g, nullptr, b1,
                                                2048, 4096, 1024, 1024, 32);
  gemm_kern<64, 3, 2><<<512, 256, 0, stream>>>(g, W2T, fbuf, o2, b2,
                                               2048, 1024, 2048, 4096, 8);
  ln_kernel<<<2048, 256, 0, stream>>>(h, fbuf, o2, ln2g, ln2b, out, nullptr);
}

// Round 8
// 244.543 us; speedup vs baseline: 1.0477x; 1.0162x over previous
//
#include <hip/hip_runtime.h>
#include <hip/hip_bf16.h>
#include <cstdint>

#define S_ 2048
#define M_ 512
#define L_ 2560
#define D_ 1024
#define F_ 4096
#define H_ 16
#define DH_ 64
#define W_ 256
#define NR_ 513
#define NRP_ 640

typedef unsigned int uint32;
typedef __attribute__((ext_vector_type(8))) short bf16x8;
typedef __attribute__((ext_vector_type(4))) float f32x4;

__device__ __forceinline__ ushort f2bf(float f) {
  uint32 u = __builtin_bit_cast(uint32, f);
  u += 0x7FFFu + ((u >> 16) & 1u);
  return (ushort)(u >> 16);
}
__device__ __forceinline__ float bf2f(ushort s) {
  uint32 u = ((uint32)s) << 16;
  return __builtin_bit_cast(float, u);
}
__device__ __forceinline__ ushort4 pack4(float4 vf) {
  ushort4 r;
  r.x = f2bf(vf.x); r.y = f2bf(vf.y); r.z = f2bf(vf.z); r.w = f2bf(vf.w);
  return r;
}
__device__ __forceinline__ float gelu_tanh(float x) {
  float t = 0.7978845608028654f * x * (1.f + 0.044715f * x * x);
  float e = __expf(2.f * t);
  float th = 1.f - 2.f / (e + 1.f);
  return 0.5f * x * (1.f + th);
}

// async global(16B/lane) -> LDS, wave-uniform LDS base + lane*16
__device__ __forceinline__ void gld_lds16(const ushort* g, ushort* l) {
  __builtin_amdgcn_global_load_lds((const __attribute__((address_space(1))) void*)g,
                                   (__attribute__((address_space(3))) void*)l, 16, 0, 0);
}

// ================= fused prep: 7 weight transposes + kv pack + sinusoid =================
__device__ __forceinline__ void tr_tile(const float* __restrict__ in, ushort* __restrict__ out,
                                        int R, int C, int c0, int r0, int tx, int ty,
                                        float (*tile)[33]) {
#pragma unroll
  for (int i = 0; i < 4; i++)
    tile[ty + i * 8][tx] = in[(size_t)(r0 + ty + i * 8) * C + c0 + tx];
  __syncthreads();
#pragma unroll
  for (int i = 0; i < 4; i++)
    out[(size_t)(c0 + ty + i * 8) * R + r0 + tx] = f2bf(tile[tx][ty + i * 8]);
}

__global__ __launch_bounds__(256)
void prep_kernel(const float* __restrict__ x, const float* __restrict__ mem,
                 const float* __restrict__ Wq, const float* __restrict__ Wk,
                 const float* __restrict__ Wv, const float* __restrict__ Wo,
                 const float* __restrict__ Wr, const float* __restrict__ W1,
                 const float* __restrict__ W2,
                 ushort* __restrict__ WqT, ushort* __restrict__ WkT,
                 ushort* __restrict__ WvT, ushort* __restrict__ WoT,
                 ushort* __restrict__ WrT, ushort* __restrict__ W1T,
                 ushort* __restrict__ W2T,
                 ushort* __restrict__ kvb, ushort* __restrict__ remb) {
  __shared__ float tile[32][33];
  const int bid = blockIdx.x;
  const int tid = threadIdx.x;
  const int tx = tid & 31, ty = tid >> 5;

  if (bid < 5120) {
    const int which = bid >> 10, idx = bid & 1023;
    const float* ins[5] = {Wq, Wk, Wv, Wo, Wr};
    ushort* outs[5] = {WqT, WkT, WvT, WoT, WrT};
    tr_tile(ins[which], outs[which], 1024, 1024, (idx & 31) * 32, (idx >> 5) * 32, tx, ty, tile);
  } else if (bid < 9216) {
    const int idx = bid - 5120;
    tr_tile(W1, W1T, 1024, 4096, (idx % 128) * 32, (idx / 128) * 32, tx, ty, tile);
  } else if (bid < 13312) {
    const int idx = bid - 9216;
    tr_tile(W2, W2T, 4096, 1024, (idx & 31) * 32, (idx >> 5) * 32, tx, ty, tile);
  } else if (bid < 15872) {
    const int k = (bid - 13312) * 256 + tid;
    const int l = k >> 8, c = k & 255;
    const float4* src = (l < M_) ? (const float4*)(mem + (size_t)l * D_)
                                 : (const float4*)(x + (size_t)(l - M_) * D_);
    ((ushort4*)kvb)[k] = pack4(src[c]);
  } else {
    const int idx = (bid - 15872) * 256 + tid;
    const int r = idx >> 9, f = idx & 511;
    if (r < NR_) {
      float invf = expf(-(float)f * (9.210340371976184f / 512.0f));
      float ang = (float)(r - W_) * invf;
      remb[(size_t)r * D_ + f] = f2bf(sinf(ang));
      remb[(size_t)r * D_ + 512 + f] = f2bf(cosf(ang));
    } else if (r < NRP_) {
      remb[(size_t)r * D_ + f] = 0;
      remb[(size_t)r * D_ + 512 + f] = 0;
    }
  }
}

// ====== MFMA GEMM core: BK=64, 2-phase (STAGE next -> compute cur -> vmcnt(0)+barrier) ======
// C[M,N] = A[M,K] x BT[N,K]^T, bf16 in. BN=128. 1D grid with XCD-bijective swizzle.
// EPI: 0 bf16; 1 f32 (SPLITK2: z=0->Cout, z=1->Cout2); 2 bf16(gelu(c+bias));
//      3 f32(c+bias) (SPLITK2: z=1->Cout2, no bias); 5 split kb/Vt.
template <int BM, int EPI, int SPLITK>
__device__ __forceinline__
void gemm_core(const ushort* __restrict__ A, const ushort* __restrict__ BT,
               void* __restrict__ Cout, void* __restrict__ Cout2,
               const float* __restrict__ bias, int Msz, int Nsz, int Ksz, int Kstride,
               int gx, int bid, int nwg, ushort* smem) {
  constexpr int PA = BM * 8 + 16;       // halfwords per kg-block (A)
  constexpr int PB = 128 * 8 + 16;
  constexpr int MFR = BM / 32;
  constexpr int NAI = (BM / 64) * 8;    // A stage instructions per block per tile
  constexpr int NPW = (NAI + 16) / 4;   // stage instructions per wave
  const int tid = threadIdx.x;
  const int wave = tid >> 6, lane = tid & 63;
  const int wr = wave >> 1, wc = wave & 1;

  const int q = nwg >> 3;
  const int swz = (bid & 7) * q + (bid >> 3);
  const int gy = Msz / BM;
  const int bx = swz % gx;
  const int rest = swz / gx;
  const int by = rest % gy;
  const int bz = rest / gy;

  const int brow = by * BM, bcol = bx * 128;
  const int koff = (SPLITK == 2) ? bz * Ksz : 0;

  ushort* As = smem;                    // 2 bufs x 8*PA
  ushort* Bs = smem + 2 * 8 * PA;       // 2 bufs x 8*PB

  const ushort* gsrc[NPW]; int ldst[NPW];
#pragma unroll
  for (int i = 0; i < NPW; i++) {
    const int idx = i * 4 + wave;
    if (i < NAI / 4) {                  // compile-time split: A insts first
      const int rowbase = (idx >> 3) * 64, kg = idx & 7;
      gsrc[i] = A + (size_t)(brow + rowbase + lane) * Kstride + koff + kg * 8;
      ldst[i] = kg * PA + rowbase * 8;
    } else {
      const int b = idx - NAI;
      const int rowbase = (b >> 3) * 64, kg = b & 7;
      gsrc[i] = BT + (size_t)(bcol + rowbase + lane) * Kstride + koff + kg * 8;
      ldst[i] = kg * PB + rowbase * 8;
    }
  }

  f32x4 acc[MFR][4] = {};
  const int kgf = lane >> 4, fr = lane & 15;
  const int nk = Ksz >> 6;              // BK = 64

  auto stage = [&](int t, int buf) {
    const int ko = t * 64;
    ushort* ab = As + buf * 8 * PA;
    ushort* bb = Bs + buf * 8 * PB;
#pragma unroll
    for (int i = 0; i < NPW; i++) {
      ushort* base = (i < NAI / 4) ? ab : bb;
      gld_lds16(gsrc[i] + ko, base + ldst[i]);
    }
  };

  stage(0, 0);
  asm volatile("s_waitcnt vmcnt(0)" ::: "memory");
  __builtin_amdgcn_s_barrier();
  __builtin_amdgcn_sched_barrier(0);

  int cur = 0;
  for (int t = 0; t < nk; t++) {
    if (t + 1 < nk) stage(t + 1, cur ^ 1);   // issue next-tile loads FIRST
    ushort* ab = As + cur * 8 * PA;
    ushort* bb = Bs + cur * 8 * PB;
#pragma unroll
    for (int kk = 0; kk < 2; kk++) {
      bf16x8 af[MFR], bfv[4];
#pragma unroll
      for (int m = 0; m < MFR; m++)
        af[m] = *(const bf16x8*)(ab + (kk * 4 + kgf) * PA + (wr * (BM / 2) + m * 16 + fr) * 8);
#pragma unroll
      for (int n = 0; n < 4; n++)
        bfv[n] = *(const bf16x8*)(bb + (kk * 4 + kgf) * PB + (wc * 64 + n * 16 + fr) * 8);
#pragma unroll
      for (int m = 0; m < MFR; m++)
#pragma unroll
        for (int n = 0; n < 4; n++)
          acc[m][n] = __builtin_amdgcn_mfma_f32_16x16x32_bf16(af[m], bfv[n], acc[m][n], 0, 0, 0);
    }
    if (t + 1 < nk) {
      asm volatile("s_waitcnt vmcnt(0)" ::: "memory");
      __builtin_amdgcn_s_barrier();
      __builtin_amdgcn_sched_barrier(0);
    }
    cur ^= 1;
  }

  const int r4 = (lane >> 4) * 4;
  float* co = (float*)Cout;
  bool addb = (EPI == 3);
  if constexpr (SPLITK == 2) {
    if (bz == 1) { co = (float*)Cout2; addb = false; }
  }
#pragma unroll
  for (int m = 0; m < MFR; m++) {
#pragma unroll
    for (int n = 0; n < 4; n++) {
      const int col = bcol + wc * 64 + n * 16 + fr;
      if constexpr (EPI == 5) {
        if (col < 1024) {
#pragma unroll
          for (int r = 0; r < 4; r++) {
            const int row = brow + wr * (BM / 2) + m * 16 + r4 + r;
            ((ushort*)Cout)[(size_t)row * 1024 + col] = f2bf(acc[m][n][r]);
          }
        } else {
          const int row0 = brow + wr * (BM / 2) + m * 16 + r4;
          ushort4 pk;
          pk.x = f2bf(acc[m][n][0]); pk.y = f2bf(acc[m][n][1]);
          pk.z = f2bf(acc[m][n][2]); pk.w = f2bf(acc[m][n][3]);
          *(ushort4*)((ushort*)Cout2 + (size_t)(col - 1024) * Msz + row0) = pk;
        }
      } else {
#pragma unroll
        for (int r = 0; r < 4; r++) {
          const int row = brow + wr * (BM / 2) + m * 16 + r4 + r;
          float val = acc[m][n][r];
          size_t o = (size_t)row * Nsz + col;
          if constexpr (EPI == 0) ((ushort*)Cout)[o] = f2bf(val);
          else if constexpr (EPI == 2) ((ushort*)Cout)[o] = f2bf(gelu_tanh(val + bias[col]));
          else co[o] = addb ? val + bias[col] : val;
        }
      }
    }
  }
}

template <int BM, int EPI, int SPLITK>
__global__ __launch_bounds__(256)
void gemm_kern(const ushort* __restrict__ A, const ushort* __restrict__ BT,
               void* __restrict__ Cout, void* __restrict__ Cout2,
               const float* __restrict__ bias, int Msz, int Nsz, int Ksz, int Kstride,
               int gx) {
  constexpr int PA = BM * 8 + 16, PB = 128 * 8 + 16;
  __shared__ __align__(16) ushort smem[2 * 8 * (PA + PB)];
  gemm_core<BM, EPI, SPLITK>(A, BT, Cout, Cout2, bias, Msz, Nsz, Ksz, Kstride,
                             gx, blockIdx.x, gridDim.x, smem);
}

// merged Q / KV / R projection: 256 + 640 + 80 = 976 blocks
__global__ __launch_bounds__(256)
void proj_gemm(const ushort* __restrict__ kvb, const ushort* __restrict__ WqT,
               const ushort* __restrict__ WkvT, const ushort* __restrict__ WrT,
               const ushort* __restrict__ remb,
               ushort* __restrict__ qb, ushort* __restrict__ kb,
               ushort* __restrict__ Vt, ushort* __restrict__ Rb) {
  __shared__ __align__(16) ushort smem[2 * 8 * (64 * 8 + 16 + 128 * 8 + 16)];
  const int bid = blockIdx.x;
  if (bid < 256) {
    gemm_core<64, 0, 1>(kvb + 512 * 1024, WqT, qb, nullptr, nullptr,
                        2048, 1024, 1024, 1024, 8, bid, 256, smem);
  } else if (bid < 896) {
    gemm_core<64, 5, 1>(kvb, WkvT, kb, Vt, nullptr,
                        2560, 2048, 1024, 1024, 16, bid - 256, 640, smem);
  } else {
    gemm_core<64, 0, 1>(remb, WrT, Rb, nullptr, nullptr,
                        640, 1024, 1024, 1024, 8, bid - 896, 80, smem);
  }
}

// ---------------- banded attention v6: lazy-max, per-lane partial l, setprio ----------
__global__ __launch_bounds__(256)
void attn_mfma4(const ushort* __restrict__ qb, const ushort* __restrict__ kb,
                const ushort* __restrict__ Vt, const ushort* __restrict__ Rb,
                const float* __restrict__ ubias, const float* __restrict__ vbias,
                ushort* __restrict__ attb) {
  const int bid = blockIdx.x;
  const int swz = (bid & 7) * 64 + (bid >> 3);
  const int h = swz >> 5;
  const int i0 = (swz & 31) * 64;
  const int tid = threadIdx.x;
  const int wave = tid >> 6, lane = tid & 63;
  const int g = lane >> 4, fr = lane & 15;
  const int hD = h * DH_;

  __shared__ __align__(16) ushort ring[4][16][64];
  __shared__ __align__(16) ushort Pl[4][16][40];

  const int qi = i0 + wave * 16 + fr;
  bf16x8 afu[2], afv[2];
#pragma unroll
  for (int kst = 0; kst < 2; kst++) {
    const int dof = kst * 32 + g * 8;
    bf16x8 qv = *(const bf16x8*)(qb + (size_t)qi * D_ + hD + dof);
    const float* up = ubias + hD + dof;
    const float* vp = vbias + hD + dof;
    bf16x8 au, av;
#pragma unroll
    for (int j = 0; j < 8; j++) {
      float q = bf2f((ushort)qv[j]);
      au[j] = (short)f2bf(q + up[j]);
      av[j] = (short)f2bf(q + vp[j]);
    }
    afu[kst] = au; afv[kst] = av;
  }

  const int jb = 256 + i0;
  const int smax = 2303 - i0;
  const int sbase = wave * 16;

  auto produce = [&](int r0, bf16x8 rf0, bf16x8 rf1) {
    f32x4 acc = {};
    __builtin_amdgcn_s_setprio(1);
    acc = __builtin_amdgcn_mfma_f32_16x16x32_bf16(afv[0], rf0, acc, 0, 0, 0);
    acc = __builtin_amdgcn_mfma_f32_16x16x32_bf16(afv[1], rf1, acc, 0, 0, 0);
    __builtin_amdgcn_s_setprio(0);
#pragma unroll
    for (int rr = 0; rr < 4; rr++)
      ring[wave][g * 4 + rr][(r0 + fr) & 63] = f2bf(acc[rr]);
  };
  auto loadRrow = [&](int row, bf16x8* out0, bf16x8* out1) {
    const int rc = row < 0 ? 0 : row;
    *out0 = *(const bf16x8*)(Rb + (size_t)rc * D_ + hD + g * 8);
    *out1 = *(const bf16x8*)(Rb + (size_t)rc * D_ + hD + 32 + g * 8);
  };
  auto loadK = [&](int ch, bf16x8 (&kp)[2][2]) {
#pragma unroll
    for (int half = 0; half < 2; half++) {
      const int sa = sbase + ch * 32 + half * 16 + fr;
      const int jc = (jb + sa < L_ - 1) ? (jb + sa) : (L_ - 1);
      kp[half][0] = *(const bf16x8*)(kb + (size_t)jc * 1024 + hD + g * 8);
      kp[half][1] = *(const bf16x8*)(kb + (size_t)jc * 1024 + hD + 32 + g * 8);
    }
  };
  auto loadV = [&](int ch, bf16x8 (&vp)[4]) {
    int kc = jb + sbase + ch * 32 + g * 8;
    if (kc > L_ - 8) kc = L_ - 8;
#pragma unroll
    for (int n = 0; n < 4; n++)
      vp[n] = *(const bf16x8*)(Vt + (size_t)(hD + n * 16 + fr) * L_ + kc);
  };

#pragma unroll
  for (int t = 0; t < 3; t++) {
    const int r0 = 480 + t * 16;
    bf16x8 rf0, rf1;
    loadRrow(r0 + fr, &rf0, &rf1);
    produce(r0, rf0, rf1);
  }

  float m4[4], l4[4];
  f32x4 oacc[4] = {};
#pragma unroll
  for (int rr = 0; rr < 4; rr++) { m4[rr] = -1e30f; l4[rr] = 0.f; }

  bf16x8 kA[2][2], vA[4], kB[2][2], vB[4];
  bf16x8 rP0a, rP0b, rP1a, rP1b;
  loadK(0, kA); loadV(0, vA);

  auto body = [&](int ch, bf16x8 (&kU)[2][2], bf16x8 (&vU)[4],
                  bf16x8 (&kP)[2][2], bf16x8 (&vP)[4], bool first) -> bool {
    const int c0 = sbase + ch * 32;
    if (c0 > smax) return false;
    if (!first) {
      const int r0 = 480 - ch * 32;
      produce(r0, rP0a, rP0b);
      produce(r0 + 16, rP1a, rP1b);
    }
    if (ch < 16) {
      const int r0n = 480 - (ch + 1) * 32;
      loadRrow(r0n + fr, &rP0a, &rP0b);
      loadRrow(r0n + 16 + fr, &rP1a, &rP1b);
      loadK(ch + 1, kP);
      loadV(ch + 1, vP);
    }
    f32x4 sc[2];
#pragma unroll
    for (int half = 0; half < 2; half++) {
      f32x4 acc = {};
      __builtin_amdgcn_s_setprio(1);
      acc = __builtin_amdgcn_mfma_f32_16x16x32_bf16(afu[0], kU[half][0], acc, 0, 0, 0);
      acc = __builtin_amdgcn_mfma_f32_16x16x32_bf16(afu[1], kU[half][1], acc, 0, 0, 0);
      __builtin_amdgcn_s_setprio(0);
      const int rb2 = 512 + g * 4 - (ch * 32 + half * 16 + fr);
      const int sa = c0 + half * 16 + fr;
#pragma unroll
      for (int rr = 0; rr < 4; rr++) {
        const int r = rb2 + rr;
        const float bd = bf2f(ring[wave][g * 4 + rr][r & 63]);
        const bool valid = ((unsigned)r <= 512u) && (sa <= smax);
        sc[half][rr] = valid ? (acc[rr] + bd) * 0.125f : -1e30f;
      }
    }
    if (first) {
      f32x4 cm;
#pragma unroll
      for (int rr = 0; rr < 4; rr++) cm[rr] = fmaxf(sc[0][rr], sc[1][rr]);
#pragma unroll
      for (int off = 8; off; off >>= 1)
#pragma unroll
        for (int rr = 0; rr < 4; rr++) cm[rr] = fmaxf(cm[rr], __shfl_xor(cm[rr], off));
#pragma unroll
      for (int rr = 0; rr < 4; rr++) m4[rr] = cm[rr];
    } else {
      bool rise = false;
#pragma unroll
      for (int rr = 0; rr < 4; rr++)
        rise |= (fmaxf(sc[0][rr], sc[1][rr]) > m4[rr] + 8.f);
      if (__any(rise)) {
        f32x4 cm;
#pragma unroll
        for (int rr = 0; rr < 4; rr++) cm[rr] = fmaxf(sc[0][rr], sc[1][rr]);
#pragma unroll
        for (int off = 8; off; off >>= 1)
#pragma unroll
          for (int rr = 0; rr < 4; rr++) cm[rr] = fmaxf(cm[rr], __shfl_xor(cm[rr], off));
#pragma unroll
        for (int rr = 0; rr < 4; rr++) {
          const float nm = fmaxf(m4[rr], cm[rr]);
          const float esc = __expf(m4[rr] - nm);
          m4[rr] = nm;
          l4[rr] *= esc;
#pragma unroll
          for (int n = 0; n < 4; n++) oacc[n][rr] *= esc;
        }
      }
    }
    f32x4 pA, pB;
#pragma unroll
    for (int rr = 0; rr < 4; rr++) {
      pA[rr] = __expf(sc[0][rr] - m4[rr]);
      pB[rr] = __expf(sc[1][rr] - m4[rr]);
      l4[rr] += pA[rr] + pB[rr];
    }
#pragma unroll
    for (int rr = 0; rr < 4; rr++) {
      Pl[wave][g * 4 + rr][fr]      = f2bf(pA[rr]);
      Pl[wave][g * 4 + rr][16 + fr] = f2bf(pB[rr]);
    }
    bf16x8 pf = *(const bf16x8*)&Pl[wave][fr][g * 8];
    __builtin_amdgcn_s_setprio(1);
#pragma unroll
    for (int n = 0; n < 4; n++)
      oacc[n] = __builtin_amdgcn_mfma_f32_16x16x32_bf16(pf, vU[n], oacc[n], 0, 0, 0);
    __builtin_amdgcn_s_setprio(0);
    return true;
  };

  bool cont = body(0, kA, vA, kB, vB, true);
  for (int ch = 1; ch < 17 && cont; ch += 2) {
    cont = body(ch, kB, vB, kA, vA, false);
    if (!cont || ch + 1 >= 17) break;
    cont = body(ch + 1, kA, vA, kB, vB, false);
  }

#pragma unroll
  for (int off = 8; off; off >>= 1)
#pragma unroll
    for (int rr = 0; rr < 4; rr++) l4[rr] += __shfl_xor(l4[rr], off);
#pragma unroll
  for (int rr = 0; rr < 4; rr++) {
    const float inv = 1.f / l4[rr];
    const size_t rowo = (size_t)(i0 + sbase + g * 4 + rr) * D_ + hD;
#pragma unroll
    for (int n = 0; n < 4; n++)
      attb[rowo + n * 16 + fr] = f2bf(oacc[n][rr] * inv);
  }
}

// ---------------- residual + LayerNorm (2 or 3 addends) ----------------
__global__ __launch_bounds__(256)
void ln_kernel(const float* __restrict__ a, const float* __restrict__ b,
               const float* __restrict__ c,
               const float* __restrict__ gamma, const float* __restrict__ beta,
               float* __restrict__ outf, ushort* __restrict__ outb) {
  const int row = blockIdx.x;
  const int tid = threadIdx.x;
  const int wave = tid >> 6, lane = tid & 63;
  float4 va = ((const float4*)(a + (size_t)row * D_))[tid];
  float4 vb4 = ((const float4*)(b + (size_t)row * D_))[tid];
  float4 xv;
  xv.x = va.x + vb4.x; xv.y = va.y + vb4.y; xv.z = va.z + vb4.z; xv.w = va.w + vb4.w;
  if (c) {
    float4 vc = ((const float4*)(c + (size_t)row * D_))[tid];
    xv.x += vc.x; xv.y += vc.y; xv.z += vc.z; xv.w += vc.w;
  }
  float s = xv.x + xv.y + xv.z + xv.w;
  float q = xv.x * xv.x + xv.y * xv.y + xv.z * xv.z + xv.w * xv.w;
#pragma unroll
  for (int off = 32; off; off >>= 1) { s += __shfl_xor(s, off); q += __shfl_xor(q, off); }
  __shared__ float red[8];
  if (lane == 0) { red[wave * 2] = s; red[wave * 2 + 1] = q; }
  __syncthreads();
  float ts = red[0] + red[2] + red[4] + red[6];
  float tq = red[1] + red[3] + red[5] + red[7];
  float mu = ts * (1.f / D_);
  float var = tq * (1.f / D_) - mu * mu;
  float rs = rsqrtf(var + 1e-5f);
  float4 g4 = ((const float4*)gamma)[tid];
  float4 be4 = ((const float4*)beta)[tid];
  float4 y;
  y.x = (xv.x - mu) * rs * g4.x + be4.x;
  y.y = (xv.y - mu) * rs * g4.y + be4.y;
  y.z = (xv.z - mu) * rs * g4.z + be4.z;
  y.w = (xv.w - mu) * rs * g4.w + be4.w;
  ((float4*)(outf + (size_t)row * D_))[tid] = y;
  if (outb) ((ushort4*)(outb + (size_t)row * D_))[tid] = pack4(y);
}

extern "C" void kernel_launch(void* const* d_in, const int* in_sizes, int n_in,
                              void* d_out, int out_size, void* d_ws, size_t ws_size,
                              hipStream_t stream) {
  const float* x    = (const float*)d_in[0];
  const float* mem  = (const float*)d_in[1];
  const float* Wq   = (const float*)d_in[2];
  const float* Wk   = (const float*)d_in[3];
  const float* Wv   = (const float*)d_in[4];
  const float* Wo   = (const float*)d_in[5];
  const float* Wr   = (const float*)d_in[6];
  const float* u    = (const float*)d_in[7];
  const float* v    = (const float*)d_in[8];
  const float* ln1g = (const float*)d_in[9];
  const float* ln1b = (const float*)d_in[10];
  const float* W1   = (const float*)d_in[11];
  const float* b1   = (const float*)d_in[12];
  const float* W2   = (const float*)d_in[13];
  const float* b2   = (const float*)d_in[14];
  const float* ln2g = (const float*)d_in[15];
  const float* ln2b = (const float*)d_in[16];
  float* out = (float*)d_out;

  char* ws = (char*)d_ws;
  size_t off = 0;
  auto take = [&](size_t n) { char* p = ws + off; off += (n + 255) & ~(size_t)255; return p; };

  ushort* WqT = (ushort*)take(2097152);
  ushort* WkT = (ushort*)take(2097152);   // WkT||WvT contiguous = [2048][1024]
  ushort* WvT = (ushort*)take(2097152);
  ushort* WoT = (ushort*)take(2097152);
  ushort* WrT = (ushort*)take(2097152);
  ushort* W1T = (ushort*)take(8388608);   // [4096][1024]
  ushort* W2T = (ushort*)take(8388608);   // [1024][4096]

  char* regA = take(8388608);             // kvb + remb; later reused for fbuf
  ushort* kvb  = (ushort*)regA;
  ushort* remb = (ushort*)(regA + 5242880);
  float*  fbuf = (float*)regA;

  char* regB = take(20185088);            // qb,kb,Vt,Rb,attb; overlays: o2b, g
  ushort* qb   = (ushort*)regB;
  ushort* kb   = (ushort*)(regB + 4194304);
  ushort* Vt   = (ushort*)(regB + 9437184);           // [1024][2560]
  ushort* Rb   = (ushort*)(regB + 14680064);
  ushort* attb = (ushort*)(regB + 15990784);
  float*  o2b  = (float*)regB;
  ushort* g    = (ushort*)regB;

  float*  o2 = (float*)take(8388608);
  float*  h  = (float*)take(8388608);
  ushort* hb = (ushort*)take(4194304);

  prep_kernel<<<17152, 256, 0, stream>>>(x, mem, Wq, Wk, Wv, Wo, Wr, W1, W2,
                                         WqT, WkT, WvT, WoT, WrT, W1T, W2T, kvb, remb);

  proj_gemm<<<976, 256, 0, stream>>>(kvb, WqT, WkT, WrT, remb, qb, kb, Vt, Rb);

  attn_mfma4<<<512, 256, 0, stream>>>(qb, kb, Vt, Rb, u, v, attb);

  gemm_kern<64, 1, 2><<<512, 256, 0, stream>>>(attb, WoT, o2, o2b, nullptr,
                                               2048, 1024, 512, 1024, 8);
  ln_kernel<<<2048, 256, 0, stream>>>(x, o2, o2b, ln1g, ln1b, h, hb);
  gemm_kern<128, 2, 1><<<512, 256, 0, stream>>>(hb, W1T, g, nullptr, b1,
                                                2048, 4096, 1024, 1024, 32);
  gemm_kern<64, 3, 2><<<512, 256, 0, stream>>>(g, W2T, fbuf, o2, b2,
                                               2048, 1024, 2048, 4096, 8);
  ln_kernel<<<2048, 256, 0, stream>>>(h, fbuf, o2, ln2g, ln2b, out, nullptr);
}